// Round 11
// baseline (300.282 us; speedup 1.0000x reference)
//
#include <hip/hip_runtime.h>
#include <hip/hip_bf16.h>

#define N_NODES 50000
#define N_EDGES 600000
#define N_PAIRS 100000

typedef __attribute__((ext_vector_type(8))) short bf16x8;
typedef __attribute__((ext_vector_type(4))) float f32x4;

__device__ inline unsigned short f2b(float f) {
    unsigned u = __float_as_uint(f);
    unsigned r = u + 0x7fff + ((u >> 16) & 1);
    return (unsigned short)(r >> 16);
}
__device__ inline float b2f(unsigned short h) {
    return __uint_as_float(((unsigned)h) << 16);
}

// ---- MERGED prep: x->bf16 compact convert + edge-degree histogram +
// FRAGMENT-LINEAR weight transposes.
__global__ void k_prep(const float* __restrict__ x, unsigned short* __restrict__ xb16,
                       const int* __restrict__ edge_dst, int* __restrict__ deg,
                       const float* __restrict__ Ws1, const float* __restrict__ Wn1,
                       const float* __restrict__ Ws2, const float* __restrict__ Wn2,
                       const float* __restrict__ Wd1, const float* __restrict__ Wd2,
                       unsigned short* __restrict__ WT1, unsigned short* __restrict__ WT2,
                       unsigned short* __restrict__ WdT1, unsigned short* __restrict__ WdT2) {
    int idx = blockIdx.x * blockDim.x + threadIdx.x;
    if (idx < N_EDGES) atomicAdd(&deg[edge_dst[idx]], 1);
    if (idx < 98304) {
        int id = idx;
        if (id < 32768) {                      // WT1: K=256 (Ws1 | Wn1)
            int j = id & 7, g = id >> 3;
            int lane = g & 63, t = g >> 6;
            int ct = t & 7, kb = t >> 3;
            int k = kb * 32 + (lane >> 4) * 8 + j, n = ct * 16 + (lane & 15);
            float v = (k < 128) ? Ws1[k * 128 + n] : Wn1[(k - 128) * 128 + n];
            WT1[id] = f2b(v);
        } else if (id < 65536) {               // WT2: K=256 (Ws2 | Wn2)
            int r = id - 32768;
            int j = r & 7, g = r >> 3;
            int lane = g & 63, t = g >> 6;
            int ct = t & 7, kb = t >> 3;
            int k = kb * 32 + (lane >> 4) * 8 + j, n = ct * 16 + (lane & 15);
            float v = (k < 128) ? Ws2[k * 128 + n] : Wn2[(k - 128) * 128 + n];
            WT2[r] = f2b(v);
        } else if (id < 81920) {               // WdT1: K=128
            int r = id - 65536;
            int j = r & 7, g = r >> 3;
            int lane = g & 63, t = g >> 6;
            int ct = t & 7, kb = t >> 3;
            int k = kb * 32 + (lane >> 4) * 8 + j, n = ct * 16 + (lane & 15);
            WdT1[r] = f2b(Wd1[k * 128 + n]);
        } else {                               // WdT2: K=128
            int r = id - 81920;
            int j = r & 7, g = r >> 3;
            int lane = g & 63, t = g >> 6;
            int ct = t & 7, kb = t >> 3;
            int k = kb * 32 + (lane >> 4) * 8 + j, n = ct * 16 + (lane & 15);
            WdT2[r] = f2b(Wd2[k * 128 + n]);
        }
    }
    if (idx >= N_NODES * 32) return;
    int row = idx >> 5, c4 = (idx & 31) * 4;
    float4 v = *(const float4*)(x + row * 128 + c4);
    unsigned lo = (unsigned)f2b(v.x) | ((unsigned)f2b(v.y) << 16);
    unsigned hi = (unsigned)f2b(v.z) | ((unsigned)f2b(v.w) << 16);
    uint2 o; o.x = lo; o.y = hi;
    *(uint2*)(xb16 + row * 128 + c4) = o;
}

// ---- CSR build ----
__global__ void k_scan1(const int* __restrict__ deg, int* __restrict__ row_ptr,
                        int* __restrict__ bsum, int n) {
    __shared__ int tmp[1024];
    int i = blockIdx.x * 1024 + threadIdx.x;
    int d = (i < n) ? deg[i] : 0;
    tmp[threadIdx.x] = d;
    __syncthreads();
    int run = d;
    for (int off = 1; off < 1024; off <<= 1) {
        int t = (threadIdx.x >= off) ? tmp[threadIdx.x - off] : 0;
        __syncthreads();
        run += t;
        tmp[threadIdx.x] = run;
        __syncthreads();
    }
    if (i < n) row_ptr[i] = run - d;       // block-local exclusive
    if (threadIdx.x == 1023) bsum[blockIdx.x] = run;   // block total
}

// fused: global prefix from bsum totals computed per block (<=49 adds)
__global__ void k_add(int* __restrict__ row_ptr, int* __restrict__ cursor,
                      const int* __restrict__ bsum, int n) {
    __shared__ int prefix;
    if (threadIdx.x == 0) {
        int acc = 0;
        for (int j = 0; j < (int)blockIdx.x; j++) acc += bsum[j];
        prefix = acc;
    }
    __syncthreads();
    int i = blockIdx.x * 1024 + threadIdx.x;
    if (i < n) {
        int v = row_ptr[i] + prefix;
        row_ptr[i] = v;
        cursor[i] = v;
    }
    if (i == 0) row_ptr[n] = N_EDGES;
}

__global__ void k_scatter(const int* __restrict__ src, const int* __restrict__ dst,
                          int* __restrict__ cursor, int* __restrict__ colA) {
    int e = blockIdx.x * blockDim.x + threadIdx.x;
    if (e < N_EDGES) {
        int d = dst[e];
        int slot = atomicAdd(&cursor[d], 1);
        colA[slot] = src[e];
    }
}

// ---- FUSED SAGE layer v2: gather/self-GEMM INTERLEAVED.
// Round-10 fusion lost gather MLP (3128 waves vs k_agg's 12500 — 2.6x fewer
// outstanding loads/CU); v2 restores overlap WITHIN each wave: per round r,
// accumulate round-r gather, issue round-(r+1)'s 16 gathers (single v buffer,
// v11 rotation), then run self-half MFMA kbi=r under those loads' latency
// (self-half is gather-independent). row_ptr/first-chunk colA prefetched for
// all 4 rounds. MFMA order kbi 0..7 unchanged -> bit-identical output.
// VGPR ~190 -> __launch_bounds__(512,2) (cap 256; plain (512) capped v10's
// k_mlp at 128 and spilled).
__global__ __launch_bounds__(512, 2) void k_fused(const unsigned short* __restrict__ selfB,
                                                  const int* __restrict__ row_ptr,
                                                  const int* __restrict__ colA,
                                                  const unsigned short* __restrict__ BT,
                                                  const float* __restrict__ bias,
                                                  unsigned short* __restrict__ Hout,
                                                  int M, int relu) {
    __shared__ unsigned short mt[128][136];   // means; reused as output tile
    const int tid = threadIdx.x;
    const int wv = tid >> 6, lane = tid & 63;
    const int q = lane >> 4, ql = lane & 15;
    const int lr = lane & 15, lq = lane >> 4;
    const int r0 = blockIdx.x * 128;
    const int arow = min(r0 + wv * 16 + lr, M - 1);

    f32x4 acc[8];
    f32x4 zero = {0.f, 0.f, 0.f, 0.f};
#pragma unroll
    for (int ct = 0; ct < 8; ct++) acc[ct] = zero;

    // prefetch all 4 rounds' row bounds + first-chunk colA
    int sA[4], eA[4], ceA[4];
#pragma unroll
    for (int r = 0; r < 4; r++) {
        int i = r * 32 + wv * 4 + q;
        int wc = min(r0 + i, M - 1);
        sA[r] = row_ptr[wc];
        eA[r] = row_ptr[wc + 1];
    }
#pragma unroll
    for (int r = 0; r < 4; r++)
        ceA[r] = (sA[r] + ql < eA[r]) ? colA[sA[r] + ql] : 0;

    uint4 v[16];
    int ei[16];
    // issue round 0 chunk 0 (degree-0 rows issue junk-but-in-bounds loads;
    // predicated accumulate adds nothing — mean stays 0, matching k_agg)
    {
        int cnt0 = min(16, eA[0] - sA[0]);
#pragma unroll
        for (int j = 0; j < 16; j++) {
            int sl = (j < cnt0) ? j : (cnt0 - 1);
            ei[j] = __shfl(ceA[0], (q << 4) + sl, 64);
        }
#pragma unroll
        for (int j = 0; j < 16; j++)
            v[j] = *(const uint4*)(selfB + (size_t)ei[j] * 128 + ql * 8);
    }

#pragma unroll 1
    for (int r = 0; r < 4; r++) {
        float a[8];
#pragma unroll
        for (int j = 0; j < 8; j++) a[j] = 0.f;
        int s = sA[r], e = eA[r];
        int base = s;
        while (true) {
            int cnt = min(16, e - base);
            // accumulate current chunk from v (waits on its loads)
#pragma unroll
            for (int j = 0; j < 16; j += 2) {
                const unsigned* p0 = (const unsigned*)&v[j];
                const unsigned* p1 = (const unsigned*)&v[j + 1];
                if (j + 1 < cnt) {
#pragma unroll
                    for (int t = 0; t < 4; t++) {
                        a[2 * t] += b2f(p0[t] & 0xffff) + b2f(p1[t] & 0xffff);
                        a[2 * t + 1] += b2f(p0[t] >> 16) + b2f(p1[t] >> 16);
                    }
                } else if (j < cnt) {
#pragma unroll
                    for (int t = 0; t < 4; t++) {
                        a[2 * t] += b2f(p0[t] & 0xffff);
                        a[2 * t + 1] += b2f(p0[t] >> 16);
                    }
                }
            }
            base += 16;
            if (base >= e) break;
            // rare multi-chunk tail: load next chunk serially
            int ce = (base + ql < e) ? colA[base + ql] : 0;
            int cnt2 = min(16, e - base);
#pragma unroll
            for (int j = 0; j < 16; j++) {
                int sl = (j < cnt2) ? j : (cnt2 - 1);
                ei[j] = __shfl(ce, (q << 4) + sl, 64);
            }
#pragma unroll
            for (int j = 0; j < 16; j++)
                v[j] = *(const uint4*)(selfB + (size_t)ei[j] * 128 + ql * 8);
        }
        // write mean row
        float rd = 1.0f / (float)max(e - s, 1);
        uint4 o;
        unsigned* op = (unsigned*)&o;
#pragma unroll
        for (int t = 0; t < 4; t++)
            op[t] = (unsigned)f2b(a[2 * t] * rd) | ((unsigned)f2b(a[2 * t + 1] * rd) << 16);
        {
            int i = r * 32 + wv * 4 + q;
            if (r0 + i < M) *(uint4*)(&mt[i][ql * 8]) = o;
        }
        // issue NEXT round's chunk 0 now — its latency hides under the
        // self-half MFMA below (v is dead after the accumulate above)
        if (r < 3) {
            int cntn = min(16, eA[r + 1] - sA[r + 1]);
#pragma unroll
            for (int j = 0; j < 16; j++) {
                int sl = (j < cntn) ? j : (cntn - 1);
                ei[j] = __shfl(ceA[r + 1], (q << 4) + sl, 64);
            }
#pragma unroll
            for (int j = 0; j < 16; j++)
                v[j] = *(const uint4*)(selfB + (size_t)ei[j] * 128 + ql * 8);
        }
        // self-half MFMA kbi = r (gather-independent work)
        {
            bf16x8 wfr[8];
#pragma unroll
            for (int ct = 0; ct < 8; ct++)
                wfr[ct] = *(const bf16x8*)(BT + ((size_t)(r * 8 + ct) * 64 + lane) * 8);
            bf16x8 af = *(const bf16x8*)(selfB + (size_t)arow * 128 + r * 32 + lq * 8);
#pragma unroll
            for (int ct = 0; ct < 8; ct++)
                acc[ct] = __builtin_amdgcn_mfma_f32_16x16x32_bf16(af, wfr[ct], acc[ct], 0, 0, 0);
        }
    }
    __syncthreads();   // all waves' mt rows visible

    // mean-half MFMA kbi 4..7 (reads mt)
#pragma unroll
    for (int kbi = 4; kbi < 8; kbi++) {
        bf16x8 wf[8];
#pragma unroll
        for (int ct = 0; ct < 8; ct++)
            wf[ct] = *(const bf16x8*)(BT + ((size_t)(kbi * 8 + ct) * 64 + lane) * 8);
        bf16x8 af = *(const bf16x8*)(&mt[arow - r0][(kbi - 4) * 32 + lq * 8]);
#pragma unroll
        for (int ct = 0; ct < 8; ct++)
            acc[ct] = __builtin_amdgcn_mfma_f32_16x16x32_bf16(af, wf[ct], acc[ct], 0, 0, 0);
    }
    // all waves must finish READING mt before it is reused as the output tile
    __syncthreads();
#pragma unroll
    for (int ct = 0; ct < 8; ct++) {
        int colc = ct * 16 + lr;
        float bv = bias[colc];
#pragma unroll
        for (int r = 0; r < 4; r++) {
            float v2 = acc[ct][r] + bv;
            if (relu) v2 = fmaxf(v2, 0.f);
            mt[wv * 16 + lq * 4 + r][colc] = f2b(v2);
        }
    }
    __syncthreads();
    // vectorized store: 4 lanes/row, 4x16B/lane -> full-line 64B segments
    int rr = tid >> 2, cc = tid & 3;
    int grow = r0 + rr;
    if (grow < M) {
#pragma unroll
        for (int c = 0; c < 4; c++) {
            int so = c * 32 + cc * 8;
            *(uint4*)(Hout + (size_t)grow * 128 + so) = *(const uint4*)(&mt[rr][so]);
        }
    }
}

// ---- decoder MLP v11 (kept): persistent 8-wave blocks, weights in LDS,
// static schedule, single-buffer gather prefetch. At its gather-service
// floor (~37-40us, rounds 4-7) — no further edits.
__global__ __launch_bounds__(512, 2) void k_mlp(const unsigned short* __restrict__ h2b,
                                                const int* __restrict__ pos_src,
                                                const int* __restrict__ pos_dst,
                                                const int* __restrict__ neg_src,
                                                const int* __restrict__ neg_dst,
                                                const unsigned short* __restrict__ WdT1,
                                                const unsigned short* __restrict__ WdT2,
                                                const float* __restrict__ bd1,
                                                const float* __restrict__ bd2,
                                                const float* __restrict__ Wd3,
                                                const float* __restrict__ bd3,
                                                float* __restrict__ out, int P2) {
    __shared__ unsigned short wds[32768];        // WdT1 | WdT2, fragment-linear
    __shared__ unsigned short t1[8][32][136];    // per-wave transpose slice
    const int tid = threadIdx.x;
    {   // stage 64KB of weights, coalesced: 4096 uint4 over 512 threads
        const uint4* s1 = (const uint4*)WdT1;
        const uint4* s2 = (const uint4*)WdT2;
        uint4* d = (uint4*)wds;
#pragma unroll
        for (int i = 0; i < 4; i++) d[tid + i * 512] = s1[tid + i * 512];
#pragma unroll
        for (int i = 0; i < 4; i++) d[2048 + tid + i * 512] = s2[tid + i * 512];
    }
    __syncthreads();
    const unsigned short* wd1 = wds;
    const unsigned short* wd2 = wds + 16384;
    const int wv = tid >> 6;
    const int lane = tid & 63, lr = lane & 15, lq = lane >> 4;
    const int nw = gridDim.x << 3;               // 2048 waves
    const int nt = P2 >> 5;                      // 6250 tiles (exact)

    uint4 z[16];
    auto ISSUE = [&](int tile) {
        const int row0 = tile * 32;
        int p0 = min(row0 + lr, P2 - 1);
        int p1 = min(row0 + 16 + lr, P2 - 1);
        int s0i = (p0 < N_PAIRS) ? pos_src[p0] : neg_src[p0 - N_PAIRS];
        int d0i = (p0 < N_PAIRS) ? pos_dst[p0] : neg_dst[p0 - N_PAIRS];
        int s1i = (p1 < N_PAIRS) ? pos_src[p1] : neg_src[p1 - N_PAIRS];
        int d1i = (p1 < N_PAIRS) ? pos_dst[p1] : neg_dst[p1 - N_PAIRS];
#pragma unroll
        for (int kb = 0; kb < 4; kb++) {
            int ka = kb * 32 + lq * 8;
            z[kb]      = *(const uint4*)(h2b + (size_t)s0i * 128 + ka);
            z[4 + kb]  = *(const uint4*)(h2b + (size_t)d0i * 128 + ka);
            z[8 + kb]  = *(const uint4*)(h2b + (size_t)s1i * 128 + ka);
            z[12 + kb] = *(const uint4*)(h2b + (size_t)d1i * 128 + ka);
        }
    };

    bf16x8 af0[4], af1[4];
    auto REPACK = [&]() {
#pragma unroll
        for (int kb = 0; kb < 4; kb++) {
            unsigned r0v[4], r1v[4];
            const unsigned* a0p = (const unsigned*)&z[kb];
            const unsigned* b0p = (const unsigned*)&z[4 + kb];
            const unsigned* a1p = (const unsigned*)&z[8 + kb];
            const unsigned* b1p = (const unsigned*)&z[12 + kb];
#pragma unroll
            for (int j = 0; j < 4; j++) {
                unsigned short lo0 = f2b(b2f(a0p[j] & 0xffff) * b2f(b0p[j] & 0xffff));
                unsigned short hi0 = f2b(b2f(a0p[j] >> 16) * b2f(b0p[j] >> 16));
                r0v[j] = (unsigned)lo0 | ((unsigned)hi0 << 16);
                unsigned short lo1 = f2b(b2f(a1p[j] & 0xffff) * b2f(b1p[j] & 0xffff));
                unsigned short hi1 = f2b(b2f(a1p[j] >> 16) * b2f(b1p[j] >> 16));
                r1v[j] = (unsigned)lo1 | ((unsigned)hi1 << 16);
            }
            af0[kb] = *(const bf16x8*)r0v;
            af1[kb] = *(const bf16x8*)r1v;
        }
    };

    auto COMPUTE_REST = [&](int tile) {
        const int row0 = tile * 32;
        f32x4 zero = {0.f, 0.f, 0.f, 0.f};
        f32x4 acc[2][8];
#pragma unroll
        for (int m = 0; m < 2; m++)
#pragma unroll
            for (int ct = 0; ct < 8; ct++) acc[m][ct] = zero;
#pragma unroll
        for (int kb = 0; kb < 4; kb++) {
            bf16x8 wf[8];
#pragma unroll
            for (int ct = 0; ct < 8; ct++)
                wf[ct] = *(const bf16x8*)(wd1 + ((kb * 8 + ct) * 64 + lane) * 8);
#pragma unroll
            for (int ct = 0; ct < 8; ct++) {
                acc[0][ct] = __builtin_amdgcn_mfma_f32_16x16x32_bf16(af0[kb], wf[ct], acc[0][ct], 0, 0, 0);
                acc[1][ct] = __builtin_amdgcn_mfma_f32_16x16x32_bf16(af1[kb], wf[ct], acc[1][ct], 0, 0, 0);
            }
        }
#pragma unroll
        for (int m = 0; m < 2; m++)
#pragma unroll
            for (int ct = 0; ct < 8; ct++) {
                int colc = ct * 16 + lr;
                float bv = bd1[colc];
#pragma unroll
                for (int r = 0; r < 4; r++) {
                    float v = fmaxf(acc[m][ct][r] + bv, 0.f);
                    t1[wv][m * 16 + lq * 4 + r][colc] = f2b(v);
                }
            }
        // per-wave sync: slice t1[wv] is wave-private; drain this wave's DS ops.
        asm volatile("s_waitcnt lgkmcnt(0)" ::: "memory");
#pragma unroll
        for (int m = 0; m < 2; m++)
#pragma unroll
            for (int ct = 0; ct < 8; ct++) acc[m][ct] = zero;
#pragma unroll
        for (int kb = 0; kb < 4; kb++) {
            int ka = kb * 32 + lq * 8;
            bf16x8 wf[8];
#pragma unroll
            for (int ct = 0; ct < 8; ct++)
                wf[ct] = *(const bf16x8*)(wd2 + ((kb * 8 + ct) * 64 + lane) * 8);
            bf16x8 bf0 = *(const bf16x8*)(&t1[wv][lr][ka]);
            bf16x8 bf1 = *(const bf16x8*)(&t1[wv][16 + lr][ka]);
#pragma unroll
            for (int ct = 0; ct < 8; ct++) {
                acc[0][ct] = __builtin_amdgcn_mfma_f32_16x16x32_bf16(bf0, wf[ct], acc[0][ct], 0, 0, 0);
                acc[1][ct] = __builtin_amdgcn_mfma_f32_16x16x32_bf16(bf1, wf[ct], acc[1][ct], 0, 0, 0);
            }
        }
        float sc[2][4] = {{0.f, 0.f, 0.f, 0.f}, {0.f, 0.f, 0.f, 0.f}};
#pragma unroll
        for (int ct = 0; ct < 8; ct++) {
            int colc = ct * 16 + lr;
            float bv = bd2[colc];
            float w3 = Wd3[colc];
#pragma unroll
            for (int m = 0; m < 2; m++)
#pragma unroll
                for (int r = 0; r < 4; r++) {
                    float v = fmaxf(acc[m][ct][r] + bv, 0.f);
                    sc[m][r] += v * w3;
                }
        }
#pragma unroll
        for (int mm = 1; mm < 16; mm <<= 1)
#pragma unroll
            for (int m = 0; m < 2; m++)
#pragma unroll
                for (int r = 0; r < 4; r++) sc[m][r] += __shfl_xor(sc[m][r], mm, 64);
        if (lr == 0) {
            float b3 = bd3[0];
#pragma unroll
            for (int m = 0; m < 2; m++)
#pragma unroll
                for (int r = 0; r < 4; r++) {
                    int g = row0 + m * 16 + lq * 4 + r;
                    if (g < P2) out[g] = sc[m][r] + b3;
                }
        }
    };

    int t = blockIdx.x * 8 + wv;
    if (t >= nt) return;
    ISSUE(t);
    while (true) {
        REPACK();                       // waits on z, then z is dead
        int tn = t + nw;
        if (tn < nt) ISSUE(tn);         // next tile's loads fly under compute
        COMPUTE_REST(t);
        if (tn >= nt) break;
        t = tn;
    }
}

static inline size_t alignup(size_t v) { return (v + 255) & ~(size_t)255; }

extern "C" void kernel_launch(void* const* d_in, const int* in_sizes, int n_in,
                              void* d_out, int out_size, void* d_ws, size_t ws_size,
                              hipStream_t stream) {
    const float* x = (const float*)d_in[0];
    const int* edge_src = (const int*)d_in[1];
    const int* edge_dst = (const int*)d_in[2];
    const int* pos_src = (const int*)d_in[3];
    const int* pos_dst = (const int*)d_in[4];
    const int* neg_src = (const int*)d_in[5];
    const int* neg_dst = (const int*)d_in[6];
    const float* Ws1 = (const float*)d_in[7];
    const float* Wn1 = (const float*)d_in[8];
    const float* b1 = (const float*)d_in[9];
    const float* Ws2 = (const float*)d_in[10];
    const float* Wn2 = (const float*)d_in[11];
    const float* b2 = (const float*)d_in[12];
    const float* Wd1 = (const float*)d_in[13];
    const float* bd1 = (const float*)d_in[14];
    const float* Wd2 = (const float*)d_in[15];
    const float* bd2 = (const float*)d_in[16];
    const float* Wd3 = (const float*)d_in[17];
    const float* bd3 = (const float*)d_in[18];
    float* out = (float*)d_out;

    char* p = (char*)d_ws;
    int* deg = (int*)p;            p += alignup(N_NODES * 4);
    int* row_ptr = (int*)p;        p += alignup((N_NODES + 1) * 4);
    int* cursor = (int*)p;         p += alignup(N_NODES * 4);
    int* bsum = (int*)p;           p += alignup(64 * 4);
    int* colA = (int*)p;           p += alignup(N_EDGES * 4);
    unsigned short* h1 = (unsigned short*)p;  p += alignup((size_t)N_NODES * 128 * 2);
    unsigned short* h2b = (unsigned short*)p; p += alignup((size_t)N_NODES * 128 * 2);
    unsigned short* WT1 = (unsigned short*)p;  p += alignup(32768 * 2);
    unsigned short* WT2 = (unsigned short*)p;  p += alignup(32768 * 2);
    unsigned short* WdT1 = (unsigned short*)p; p += alignup(16384 * 2);
    unsigned short* WdT2 = (unsigned short*)p; p += alignup(16384 * 2);
    // compact bf16 copy of x, aliased onto h2b (fully consumed by fused layer 1
    // before fused layer 2 writes h2b)
    unsigned short* xb16 = h2b;

    hipMemsetAsync(deg, 0, N_NODES * 4, stream);

    // merged convert + weight-prep + degree histogram
    k_prep<<<(N_NODES * 32 + 255) / 256, 256, 0, stream>>>(
        x, xb16, edge_dst, deg,
        Ws1, Wn1, Ws2, Wn2, Wd1, Wd2, WT1, WT2, WdT1, WdT2);

    int nb1 = (N_NODES + 1023) / 1024;
    k_scan1<<<nb1, 1024, 0, stream>>>(deg, row_ptr, bsum, N_NODES);
    k_add<<<nb1, 1024, 0, stream>>>(row_ptr, cursor, bsum, N_NODES);
    k_scatter<<<(N_EDGES + 255) / 256, 256, 0, stream>>>(edge_src, edge_dst, cursor, colA);

    int nblk = (N_NODES + 127) / 128;

    // fused layer 1: agg(xb16) + GEMM -> h1 (relu)
    k_fused<<<nblk, 512, 0, stream>>>(xb16, row_ptr, colA, WT1, b1, h1, N_NODES, 1);
    // fused layer 2: agg(h1) + GEMM -> h2b (no act)
    k_fused<<<nblk, 512, 0, stream>>>(h1, row_ptr, colA, WT2, b2, h2b, N_NODES, 0);

    // decoder: persistent 8-wave blocks, LDS weights, static schedule,
    // single-buffer gather prefetch
    k_mlp<<<256, 512, 0, stream>>>(h2b, pos_src, pos_dst, neg_src, neg_dst,
                                   WdT1, WdT2, bd1, bd2, Wd3, bd3,
                                   out, N_PAIRS * 2);
}

// Round 12
// 276.268 us; speedup vs baseline: 1.0869x; 1.0869x over previous
//
#include <hip/hip_runtime.h>
#include <hip/hip_bf16.h>

#define N_NODES 50000
#define N_EDGES 600000
#define N_PAIRS 100000

typedef __attribute__((ext_vector_type(8))) short bf16x8;
typedef __attribute__((ext_vector_type(4))) float f32x4;

__device__ inline unsigned short f2b(float f) {
    unsigned u = __float_as_uint(f);
    unsigned r = u + 0x7fff + ((u >> 16) & 1);
    return (unsigned short)(r >> 16);
}
__device__ inline float b2f(unsigned short h) {
    return __uint_as_float(((unsigned)h) << 16);
}

// ---- MERGED prep: x->bf16 compact convert + edge-degree histogram +
// FRAGMENT-LINEAR weight transposes.
__global__ void k_prep(const float* __restrict__ x, unsigned short* __restrict__ xb16,
                       const int* __restrict__ edge_dst, int* __restrict__ deg,
                       const float* __restrict__ Ws1, const float* __restrict__ Wn1,
                       const float* __restrict__ Ws2, const float* __restrict__ Wn2,
                       const float* __restrict__ Wd1, const float* __restrict__ Wd2,
                       unsigned short* __restrict__ WT1, unsigned short* __restrict__ WT2,
                       unsigned short* __restrict__ WdT1, unsigned short* __restrict__ WdT2) {
    int idx = blockIdx.x * blockDim.x + threadIdx.x;
    if (idx < N_EDGES) atomicAdd(&deg[edge_dst[idx]], 1);
    if (idx < 98304) {
        int id = idx;
        if (id < 32768) {                      // WT1: K=256 (Ws1 | Wn1)
            int j = id & 7, g = id >> 3;
            int lane = g & 63, t = g >> 6;
            int ct = t & 7, kb = t >> 3;
            int k = kb * 32 + (lane >> 4) * 8 + j, n = ct * 16 + (lane & 15);
            float v = (k < 128) ? Ws1[k * 128 + n] : Wn1[(k - 128) * 128 + n];
            WT1[id] = f2b(v);
        } else if (id < 65536) {               // WT2: K=256 (Ws2 | Wn2)
            int r = id - 32768;
            int j = r & 7, g = r >> 3;
            int lane = g & 63, t = g >> 6;
            int ct = t & 7, kb = t >> 3;
            int k = kb * 32 + (lane >> 4) * 8 + j, n = ct * 16 + (lane & 15);
            float v = (k < 128) ? Ws2[k * 128 + n] : Wn2[(k - 128) * 128 + n];
            WT2[r] = f2b(v);
        } else if (id < 81920) {               // WdT1: K=128
            int r = id - 65536;
            int j = r & 7, g = r >> 3;
            int lane = g & 63, t = g >> 6;
            int ct = t & 7, kb = t >> 3;
            int k = kb * 32 + (lane >> 4) * 8 + j, n = ct * 16 + (lane & 15);
            WdT1[r] = f2b(Wd1[k * 128 + n]);
        } else {                               // WdT2: K=128
            int r = id - 81920;
            int j = r & 7, g = r >> 3;
            int lane = g & 63, t = g >> 6;
            int ct = t & 7, kb = t >> 3;
            int k = kb * 32 + (lane >> 4) * 8 + j, n = ct * 16 + (lane & 15);
            WdT2[r] = f2b(Wd2[k * 128 + n]);
        }
    }
    if (idx >= N_NODES * 32) return;
    int row = idx >> 5, c4 = (idx & 31) * 4;
    float4 v = *(const float4*)(x + row * 128 + c4);
    unsigned lo = (unsigned)f2b(v.x) | ((unsigned)f2b(v.y) << 16);
    unsigned hi = (unsigned)f2b(v.z) | ((unsigned)f2b(v.w) << 16);
    uint2 o; o.x = lo; o.y = hi;
    *(uint2*)(xb16 + row * 128 + c4) = o;
}

// ---- CSR build ----
__global__ void k_scan1(const int* __restrict__ deg, int* __restrict__ row_ptr,
                        int* __restrict__ bsum, int n) {
    __shared__ int tmp[1024];
    int i = blockIdx.x * 1024 + threadIdx.x;
    int d = (i < n) ? deg[i] : 0;
    tmp[threadIdx.x] = d;
    __syncthreads();
    int run = d;
    for (int off = 1; off < 1024; off <<= 1) {
        int t = (threadIdx.x >= off) ? tmp[threadIdx.x - off] : 0;
        __syncthreads();
        run += t;
        tmp[threadIdx.x] = run;
        __syncthreads();
    }
    if (i < n) row_ptr[i] = run - d;       // block-local exclusive
    if (threadIdx.x == 1023) bsum[blockIdx.x] = run;   // block total
}

// fused: global prefix from bsum totals computed per block (<=49 adds)
__global__ void k_add(int* __restrict__ row_ptr, int* __restrict__ cursor,
                      const int* __restrict__ bsum, int n) {
    __shared__ int prefix;
    if (threadIdx.x == 0) {
        int acc = 0;
        for (int j = 0; j < (int)blockIdx.x; j++) acc += bsum[j];
        prefix = acc;
    }
    __syncthreads();
    int i = blockIdx.x * 1024 + threadIdx.x;
    if (i < n) {
        int v = row_ptr[i] + prefix;
        row_ptr[i] = v;
        cursor[i] = v;
    }
    if (i == 0) row_ptr[n] = N_EDGES;
}

__global__ void k_scatter(const int* __restrict__ src, const int* __restrict__ dst,
                          int* __restrict__ cursor, int* __restrict__ colA) {
    int e = blockIdx.x * blockDim.x + threadIdx.x;
    if (e < N_EDGES) {
        int d = dst[e];
        int slot = atomicAdd(&cursor[d], 1);
        colA[slot] = src[e];
    }
}

// ---- FUSED SAGE layer v3: round-10 proven body (gather phase -> barrier ->
// GEMM phase; NO mid-loop MFMA — round-11's interleave regressed 13us/dispatch:
// weights-from-global issued AFTER next-round gathers forced the MFMA's
// auto-wait to vmcnt(0), draining the gathers; and 8 MFMAs (~300cy) can't hide
// ~700cy gather latency anyway) + DEPENDENCY-CHAIN PREFETCH kept from v2:
// all 4 rounds' row bounds + first-chunk colA upfront (kills the serial
// row_ptr->colA->gather chain at rounds 1-3), and next-chunk colA issued
// before the accumulate consumes v (accumulate waits on OLDER gather loads —
// no counter hazard).
__global__ __launch_bounds__(512, 2) void k_fused(const unsigned short* __restrict__ selfB,
                                                  const int* __restrict__ row_ptr,
                                                  const int* __restrict__ colA,
                                                  const unsigned short* __restrict__ BT,
                                                  const float* __restrict__ bias,
                                                  unsigned short* __restrict__ Hout,
                                                  int M, int relu) {
    __shared__ unsigned short mt[128][136];   // means; reused as output tile
    const int tid = threadIdx.x;
    const int wv = tid >> 6, lane = tid & 63;
    const int q = lane >> 4, ql = lane & 15;
    const int r0 = blockIdx.x * 128;

    // prefetch all 4 rounds' row bounds + first-chunk colA
    int sA[4], eA[4], ceA[4];
#pragma unroll
    for (int r = 0; r < 4; r++) {
        int i = r * 32 + wv * 4 + q;
        int wc = min(r0 + i, M - 1);
        sA[r] = row_ptr[wc];
        eA[r] = row_ptr[wc + 1];
    }
#pragma unroll
    for (int r = 0; r < 4; r++)
        ceA[r] = (sA[r] + ql < eA[r]) ? colA[sA[r] + ql] : 0;

    // ---- phase 1: aggregate means for nodes r0..r0+127 into mt ----
#pragma unroll 1
    for (int r = 0; r < 4; r++) {
        int i = r * 32 + wv * 4 + q;       // 0..127
        bool act = (r0 + i < M);
        int s = sA[r], e = eA[r];
        float a[8];
#pragma unroll
        for (int j = 0; j < 8; j++) a[j] = 0.f;
        int ce = ceA[r];
        for (int base = s; base < e; base += 16) {
            int cnt = min(16, e - base);
            int ei[16];
#pragma unroll
            for (int j = 0; j < 16; j++) {
                int sl = (j < cnt) ? j : (cnt - 1);
                ei[j] = __shfl(ce, (q << 4) + sl, 64);
            }
            uint4 v[16];
#pragma unroll
            for (int j = 0; j < 16; j++)
                v[j] = *(const uint4*)(selfB + (size_t)ei[j] * 128 + ql * 8);
            // prefetch next chunk's colA BEFORE consuming v (v's loads are
            // older -> accumulate waits vmcnt(1), ce stays in flight)
            if (base + 16 < e) ce = (base + 16 + ql < e) ? colA[base + 16 + ql] : 0;
#pragma unroll
            for (int j = 0; j < 16; j += 2) {
                const unsigned* p0 = (const unsigned*)&v[j];
                const unsigned* p1 = (const unsigned*)&v[j + 1];
                if (j + 1 < cnt) {
#pragma unroll
                    for (int t = 0; t < 4; t++) {
                        a[2 * t] += b2f(p0[t] & 0xffff) + b2f(p1[t] & 0xffff);
                        a[2 * t + 1] += b2f(p0[t] >> 16) + b2f(p1[t] >> 16);
                    }
                } else if (j < cnt) {
#pragma unroll
                    for (int t = 0; t < 4; t++) {
                        a[2 * t] += b2f(p0[t] & 0xffff);
                        a[2 * t + 1] += b2f(p0[t] >> 16);
                    }
                }
            }
        }
        float rd = 1.0f / (float)max(e - s, 1);
        uint4 o;
        unsigned* op = (unsigned*)&o;
#pragma unroll
        for (int t = 0; t < 4; t++)
            op[t] = (unsigned)f2b(a[2 * t] * rd) | ((unsigned)f2b(a[2 * t + 1] * rd) << 16);
        if (act) *(uint4*)(&mt[i][ql * 8]) = o;
    }
    __syncthreads();

    // ---- phase 2: GEMM, 16 rows/wave; K 0..127 = self (global), 128..255 = mean (LDS)
    const int lr = lane & 15, lq = lane >> 4;
    const int arow = min(r0 + wv * 16 + lr, M - 1);
    f32x4 acc[8];
    f32x4 zero = {0.f, 0.f, 0.f, 0.f};
#pragma unroll
    for (int ct = 0; ct < 8; ct++) acc[ct] = zero;
#pragma unroll
    for (int kbi = 0; kbi < 8; kbi++) {
        bf16x8 wf[8];
#pragma unroll
        for (int ct = 0; ct < 8; ct++)
            wf[ct] = *(const bf16x8*)(BT + ((size_t)(kbi * 8 + ct) * 64 + lane) * 8);
        bf16x8 af;
        if (kbi < 4) {
            af = *(const bf16x8*)(selfB + (size_t)arow * 128 + kbi * 32 + lq * 8);
        } else {
            af = *(const bf16x8*)(&mt[arow - r0][(kbi - 4) * 32 + lq * 8]);
        }
#pragma unroll
        for (int ct = 0; ct < 8; ct++)
            acc[ct] = __builtin_amdgcn_mfma_f32_16x16x32_bf16(af, wf[ct], acc[ct], 0, 0, 0);
    }
    // all waves must finish READING mt before it is reused as the output tile
    __syncthreads();
#pragma unroll
    for (int ct = 0; ct < 8; ct++) {
        int colc = ct * 16 + lr;
        float bv = bias[colc];
#pragma unroll
        for (int r = 0; r < 4; r++) {
            float v = acc[ct][r] + bv;
            if (relu) v = fmaxf(v, 0.f);
            mt[wv * 16 + lq * 4 + r][colc] = f2b(v);
        }
    }
    __syncthreads();
    // vectorized store: 4 lanes/row, 4x16B/lane -> full-line 64B segments
    int rr = tid >> 2, cc = tid & 3;
    int grow = r0 + rr;
    if (grow < M) {
#pragma unroll
        for (int c = 0; c < 4; c++) {
            int so = c * 32 + cc * 8;
            *(uint4*)(Hout + (size_t)grow * 128 + so) = *(const uint4*)(&mt[rr][so]);
        }
    }
}

// ---- decoder MLP v11 (kept): persistent 8-wave blocks, weights in LDS,
// static schedule, single-buffer gather prefetch. At its gather-service
// floor (~37-40us, rounds 4-7) — no further edits.
__global__ __launch_bounds__(512, 2) void k_mlp(const unsigned short* __restrict__ h2b,
                                                const int* __restrict__ pos_src,
                                                const int* __restrict__ pos_dst,
                                                const int* __restrict__ neg_src,
                                                const int* __restrict__ neg_dst,
                                                const unsigned short* __restrict__ WdT1,
                                                const unsigned short* __restrict__ WdT2,
                                                const float* __restrict__ bd1,
                                                const float* __restrict__ bd2,
                                                const float* __restrict__ Wd3,
                                                const float* __restrict__ bd3,
                                                float* __restrict__ out, int P2) {
    __shared__ unsigned short wds[32768];        // WdT1 | WdT2, fragment-linear
    __shared__ unsigned short t1[8][32][136];    // per-wave transpose slice
    const int tid = threadIdx.x;
    {   // stage 64KB of weights, coalesced: 4096 uint4 over 512 threads
        const uint4* s1 = (const uint4*)WdT1;
        const uint4* s2 = (const uint4*)WdT2;
        uint4* d = (uint4*)wds;
#pragma unroll
        for (int i = 0; i < 4; i++) d[tid + i * 512] = s1[tid + i * 512];
#pragma unroll
        for (int i = 0; i < 4; i++) d[2048 + tid + i * 512] = s2[tid + i * 512];
    }
    __syncthreads();
    const unsigned short* wd1 = wds;
    const unsigned short* wd2 = wds + 16384;
    const int wv = tid >> 6;
    const int lane = tid & 63, lr = lane & 15, lq = lane >> 4;
    const int nw = gridDim.x << 3;               // 2048 waves
    const int nt = P2 >> 5;                      // 6250 tiles (exact)

    uint4 z[16];
    auto ISSUE = [&](int tile) {
        const int row0 = tile * 32;
        int p0 = min(row0 + lr, P2 - 1);
        int p1 = min(row0 + 16 + lr, P2 - 1);
        int s0i = (p0 < N_PAIRS) ? pos_src[p0] : neg_src[p0 - N_PAIRS];
        int d0i = (p0 < N_PAIRS) ? pos_dst[p0] : neg_dst[p0 - N_PAIRS];
        int s1i = (p1 < N_PAIRS) ? pos_src[p1] : neg_src[p1 - N_PAIRS];
        int d1i = (p1 < N_PAIRS) ? pos_dst[p1] : neg_dst[p1 - N_PAIRS];
#pragma unroll
        for (int kb = 0; kb < 4; kb++) {
            int ka = kb * 32 + lq * 8;
            z[kb]      = *(const uint4*)(h2b + (size_t)s0i * 128 + ka);
            z[4 + kb]  = *(const uint4*)(h2b + (size_t)d0i * 128 + ka);
            z[8 + kb]  = *(const uint4*)(h2b + (size_t)s1i * 128 + ka);
            z[12 + kb] = *(const uint4*)(h2b + (size_t)d1i * 128 + ka);
        }
    };

    bf16x8 af0[4], af1[4];
    auto REPACK = [&]() {
#pragma unroll
        for (int kb = 0; kb < 4; kb++) {
            unsigned r0v[4], r1v[4];
            const unsigned* a0p = (const unsigned*)&z[kb];
            const unsigned* b0p = (const unsigned*)&z[4 + kb];
            const unsigned* a1p = (const unsigned*)&z[8 + kb];
            const unsigned* b1p = (const unsigned*)&z[12 + kb];
#pragma unroll
            for (int j = 0; j < 4; j++) {
                unsigned short lo0 = f2b(b2f(a0p[j] & 0xffff) * b2f(b0p[j] & 0xffff));
                unsigned short hi0 = f2b(b2f(a0p[j] >> 16) * b2f(b0p[j] >> 16));
                r0v[j] = (unsigned)lo0 | ((unsigned)hi0 << 16);
                unsigned short lo1 = f2b(b2f(a1p[j] & 0xffff) * b2f(b1p[j] & 0xffff));
                unsigned short hi1 = f2b(b2f(a1p[j] >> 16) * b2f(b1p[j] >> 16));
                r1v[j] = (unsigned)lo1 | ((unsigned)hi1 << 16);
            }
            af0[kb] = *(const bf16x8*)r0v;
            af1[kb] = *(const bf16x8*)r1v;
        }
    };

    auto COMPUTE_REST = [&](int tile) {
        const int row0 = tile * 32;
        f32x4 zero = {0.f, 0.f, 0.f, 0.f};
        f32x4 acc[2][8];
#pragma unroll
        for (int m = 0; m < 2; m++)
#pragma unroll
            for (int ct = 0; ct < 8; ct++) acc[m][ct] = zero;
#pragma unroll
        for (int kb = 0; kb < 4; kb++) {
            bf16x8 wf[8];
#pragma unroll
            for (int ct = 0; ct < 8; ct++)
                wf[ct] = *(const bf16x8*)(wd1 + ((kb * 8 + ct) * 64 + lane) * 8);
#pragma unroll
            for (int ct = 0; ct < 8; ct++) {
                acc[0][ct] = __builtin_amdgcn_mfma_f32_16x16x32_bf16(af0[kb], wf[ct], acc[0][ct], 0, 0, 0);
                acc[1][ct] = __builtin_amdgcn_mfma_f32_16x16x32_bf16(af1[kb], wf[ct], acc[1][ct], 0, 0, 0);
            }
        }
#pragma unroll
        for (int m = 0; m < 2; m++)
#pragma unroll
            for (int ct = 0; ct < 8; ct++) {
                int colc = ct * 16 + lr;
                float bv = bd1[colc];
#pragma unroll
                for (int r = 0; r < 4; r++) {
                    float v = fmaxf(acc[m][ct][r] + bv, 0.f);
                    t1[wv][m * 16 + lq * 4 + r][colc] = f2b(v);
                }
            }
        // per-wave sync: slice t1[wv] is wave-private; drain this wave's DS ops.
        asm volatile("s_waitcnt lgkmcnt(0)" ::: "memory");
#pragma unroll
        for (int m = 0; m < 2; m++)
#pragma unroll
            for (int ct = 0; ct < 8; ct++) acc[m][ct] = zero;
#pragma unroll
        for (int kb = 0; kb < 4; kb++) {
            int ka = kb * 32 + lq * 8;
            bf16x8 wf[8];
#pragma unroll
            for (int ct = 0; ct < 8; ct++)
                wf[ct] = *(const bf16x8*)(wd2 + ((kb * 8 + ct) * 64 + lane) * 8);
            bf16x8 bf0 = *(const bf16x8*)(&t1[wv][lr][ka]);
            bf16x8 bf1 = *(const bf16x8*)(&t1[wv][16 + lr][ka]);
#pragma unroll
            for (int ct = 0; ct < 8; ct++) {
                acc[0][ct] = __builtin_amdgcn_mfma_f32_16x16x32_bf16(bf0, wf[ct], acc[0][ct], 0, 0, 0);
                acc[1][ct] = __builtin_amdgcn_mfma_f32_16x16x32_bf16(bf1, wf[ct], acc[1][ct], 0, 0, 0);
            }
        }
        float sc[2][4] = {{0.f, 0.f, 0.f, 0.f}, {0.f, 0.f, 0.f, 0.f}};
#pragma unroll
        for (int ct = 0; ct < 8; ct++) {
            int colc = ct * 16 + lr;
            float bv = bd2[colc];
            float w3 = Wd3[colc];
#pragma unroll
            for (int m = 0; m < 2; m++)
#pragma unroll
                for (int r = 0; r < 4; r++) {
                    float v = fmaxf(acc[m][ct][r] + bv, 0.f);
                    sc[m][r] += v * w3;
                }
        }
#pragma unroll
        for (int mm = 1; mm < 16; mm <<= 1)
#pragma unroll
            for (int m = 0; m < 2; m++)
#pragma unroll
                for (int r = 0; r < 4; r++) sc[m][r] += __shfl_xor(sc[m][r], mm, 64);
        if (lr == 0) {
            float b3 = bd3[0];
#pragma unroll
            for (int m = 0; m < 2; m++)
#pragma unroll
                for (int r = 0; r < 4; r++) {
                    int g = row0 + m * 16 + lq * 4 + r;
                    if (g < P2) out[g] = sc[m][r] + b3;
                }
        }
    };

    int t = blockIdx.x * 8 + wv;
    if (t >= nt) return;
    ISSUE(t);
    while (true) {
        REPACK();                       // waits on z, then z is dead
        int tn = t + nw;
        if (tn < nt) ISSUE(tn);         // next tile's loads fly under compute
        COMPUTE_REST(t);
        if (tn >= nt) break;
        t = tn;
    }
}

static inline size_t alignup(size_t v) { return (v + 255) & ~(size_t)255; }

extern "C" void kernel_launch(void* const* d_in, const int* in_sizes, int n_in,
                              void* d_out, int out_size, void* d_ws, size_t ws_size,
                              hipStream_t stream) {
    const float* x = (const float*)d_in[0];
    const int* edge_src = (const int*)d_in[1];
    const int* edge_dst = (const int*)d_in[2];
    const int* pos_src = (const int*)d_in[3];
    const int* pos_dst = (const int*)d_in[4];
    const int* neg_src = (const int*)d_in[5];
    const int* neg_dst = (const int*)d_in[6];
    const float* Ws1 = (const float*)d_in[7];
    const float* Wn1 = (const float*)d_in[8];
    const float* b1 = (const float*)d_in[9];
    const float* Ws2 = (const float*)d_in[10];
    const float* Wn2 = (const float*)d_in[11];
    const float* b2 = (const float*)d_in[12];
    const float* Wd1 = (const float*)d_in[13];
    const float* bd1 = (const float*)d_in[14];
    const float* Wd2 = (const float*)d_in[15];
    const float* bd2 = (const float*)d_in[16];
    const float* Wd3 = (const float*)d_in[17];
    const float* bd3 = (const float*)d_in[18];
    float* out = (float*)d_out;

    char* p = (char*)d_ws;
    int* deg = (int*)p;            p += alignup(N_NODES * 4);
    int* row_ptr = (int*)p;        p += alignup((N_NODES + 1) * 4);
    int* cursor = (int*)p;         p += alignup(N_NODES * 4);
    int* bsum = (int*)p;           p += alignup(64 * 4);
    int* colA = (int*)p;           p += alignup(N_EDGES * 4);
    unsigned short* h1 = (unsigned short*)p;  p += alignup((size_t)N_NODES * 128 * 2);
    unsigned short* h2b = (unsigned short*)p; p += alignup((size_t)N_NODES * 128 * 2);
    unsigned short* WT1 = (unsigned short*)p;  p += alignup(32768 * 2);
    unsigned short* WT2 = (unsigned short*)p;  p += alignup(32768 * 2);
    unsigned short* WdT1 = (unsigned short*)p; p += alignup(16384 * 2);
    unsigned short* WdT2 = (unsigned short*)p; p += alignup(16384 * 2);
    // compact bf16 copy of x, aliased onto h2b (fully consumed by fused layer 1
    // before fused layer 2 writes h2b)
    unsigned short* xb16 = h2b;

    hipMemsetAsync(deg, 0, N_NODES * 4, stream);

    // merged convert + weight-prep + degree histogram
    k_prep<<<(N_NODES * 32 + 255) / 256, 256, 0, stream>>>(
        x, xb16, edge_dst, deg,
        Ws1, Wn1, Ws2, Wn2, Wd1, Wd2, WT1, WT2, WdT1, WdT2);

    int nb1 = (N_NODES + 1023) / 1024;
    k_scan1<<<nb1, 1024, 0, stream>>>(deg, row_ptr, bsum, N_NODES);
    k_add<<<nb1, 1024, 0, stream>>>(row_ptr, cursor, bsum, N_NODES);
    k_scatter<<<(N_EDGES + 255) / 256, 256, 0, stream>>>(edge_src, edge_dst, cursor, colA);

    int nblk = (N_NODES + 127) / 128;

    // fused layer 1: agg(xb16) + GEMM -> h1 (relu)
    k_fused<<<nblk, 512, 0, stream>>>(xb16, row_ptr, colA, WT1, b1, h1, N_NODES, 1);
    // fused layer 2: agg(h1) + GEMM -> h2b (no act)
    k_fused<<<nblk, 512, 0, stream>>>(h1, row_ptr, colA, WT2, b2, h2b, N_NODES, 0);

    // decoder: persistent 8-wave blocks, LDS weights, static schedule,
    // single-buffer gather prefetch
    k_mlp<<<256, 512, 0, stream>>>(h2b, pos_src, pos_dst, neg_src, neg_dst,
                                   WdT1, WdT2, bd1, bd2, Wd3, bd3,
                                   out, N_PAIRS * 2);
}

// Round 13
// 270.002 us; speedup vs baseline: 1.1121x; 1.0232x over previous
//
#include <hip/hip_runtime.h>
#include <hip/hip_bf16.h>

#define N_NODES 50000
#define N_EDGES 600000
#define N_PAIRS 100000

typedef __attribute__((ext_vector_type(8))) short bf16x8;
typedef __attribute__((ext_vector_type(4))) float f32x4;

__device__ inline unsigned short f2b(float f) {
    unsigned u = __float_as_uint(f);
    unsigned r = u + 0x7fff + ((u >> 16) & 1);
    return (unsigned short)(r >> 16);
}
__device__ inline float b2f(unsigned short h) {
    return __uint_as_float(((unsigned)h) << 16);
}

// ---- MERGED prep: x->bf16 compact convert + edge-degree histogram +
// FRAGMENT-LINEAR weight transposes.
__global__ void k_prep(const float* __restrict__ x, unsigned short* __restrict__ xb16,
                       const int* __restrict__ edge_dst, int* __restrict__ deg,
                       const float* __restrict__ Ws1, const float* __restrict__ Wn1,
                       const float* __restrict__ Ws2, const float* __restrict__ Wn2,
                       const float* __restrict__ Wd1, const float* __restrict__ Wd2,
                       unsigned short* __restrict__ WT1, unsigned short* __restrict__ WT2,
                       unsigned short* __restrict__ WdT1, unsigned short* __restrict__ WdT2) {
    int idx = blockIdx.x * blockDim.x + threadIdx.x;
    if (idx < N_EDGES) atomicAdd(&deg[edge_dst[idx]], 1);
    if (idx < 98304) {
        int id = idx;
        if (id < 32768) {                      // WT1: K=256 (Ws1 | Wn1)
            int j = id & 7, g = id >> 3;
            int lane = g & 63, t = g >> 6;
            int ct = t & 7, kb = t >> 3;
            int k = kb * 32 + (lane >> 4) * 8 + j, n = ct * 16 + (lane & 15);
            float v = (k < 128) ? Ws1[k * 128 + n] : Wn1[(k - 128) * 128 + n];
            WT1[id] = f2b(v);
        } else if (id < 65536) {               // WT2: K=256 (Ws2 | Wn2)
            int r = id - 32768;
            int j = r & 7, g = r >> 3;
            int lane = g & 63, t = g >> 6;
            int ct = t & 7, kb = t >> 3;
            int k = kb * 32 + (lane >> 4) * 8 + j, n = ct * 16 + (lane & 15);
            float v = (k < 128) ? Ws2[k * 128 + n] : Wn2[(k - 128) * 128 + n];
            WT2[r] = f2b(v);
        } else if (id < 81920) {               // WdT1: K=128
            int r = id - 65536;
            int j = r & 7, g = r >> 3;
            int lane = g & 63, t = g >> 6;
            int ct = t & 7, kb = t >> 3;
            int k = kb * 32 + (lane >> 4) * 8 + j, n = ct * 16 + (lane & 15);
            WdT1[r] = f2b(Wd1[k * 128 + n]);
        } else {                               // WdT2: K=128
            int r = id - 81920;
            int j = r & 7, g = r >> 3;
            int lane = g & 63, t = g >> 6;
            int ct = t & 7, kb = t >> 3;
            int k = kb * 32 + (lane >> 4) * 8 + j, n = ct * 16 + (lane & 15);
            WdT2[r] = f2b(Wd2[k * 128 + n]);
        }
    }
    if (idx >= N_NODES * 32) return;
    int row = idx >> 5, c4 = (idx & 31) * 4;
    float4 v = *(const float4*)(x + row * 128 + c4);
    unsigned lo = (unsigned)f2b(v.x) | ((unsigned)f2b(v.y) << 16);
    unsigned hi = (unsigned)f2b(v.z) | ((unsigned)f2b(v.w) << 16);
    uint2 o; o.x = lo; o.y = hi;
    *(uint2*)(xb16 + row * 128 + c4) = o;
}

// ---- CSR build ----
__global__ void k_scan1(const int* __restrict__ deg, int* __restrict__ row_ptr,
                        int* __restrict__ bsum, int n) {
    __shared__ int tmp[1024];
    int i = blockIdx.x * 1024 + threadIdx.x;
    int d = (i < n) ? deg[i] : 0;
    tmp[threadIdx.x] = d;
    __syncthreads();
    int run = d;
    for (int off = 1; off < 1024; off <<= 1) {
        int t = (threadIdx.x >= off) ? tmp[threadIdx.x - off] : 0;
        __syncthreads();
        run += t;
        tmp[threadIdx.x] = run;
        __syncthreads();
    }
    if (i < n) row_ptr[i] = run - d;       // block-local exclusive
    if (threadIdx.x == 1023) bsum[blockIdx.x] = run;   // block total
}

// fused: global prefix from bsum totals computed per block (<=49 adds)
__global__ void k_add(int* __restrict__ row_ptr, int* __restrict__ cursor,
                      const int* __restrict__ bsum, int n) {
    __shared__ int prefix;
    if (threadIdx.x == 0) {
        int acc = 0;
        for (int j = 0; j < (int)blockIdx.x; j++) acc += bsum[j];
        prefix = acc;
    }
    __syncthreads();
    int i = blockIdx.x * 1024 + threadIdx.x;
    if (i < n) {
        int v = row_ptr[i] + prefix;
        row_ptr[i] = v;
        cursor[i] = v;
    }
    if (i == 0) row_ptr[n] = N_EDGES;
}

__global__ void k_scatter(const int* __restrict__ src, const int* __restrict__ dst,
                          int* __restrict__ cursor, int* __restrict__ colA) {
    int e = blockIdx.x * blockDim.x + threadIdx.x;
    if (e < N_EDGES) {
        int d = dst[e];
        int slot = atomicAdd(&cursor[d], 1);
        colA[slot] = src[e];
    }
}

// ---- FUSED SAGE layer v4: round-12 proven body at 64-ROW TILES / 4-WAVE
// BLOCKS. Round-11/12 counters showed the latency-bound gather phase starved
// at ~5 waves/CU average — NOT a cap (VGPR 104 -> 16 waves/CU ok; LDS ok) but
// GRID granularity: 391 blocks / 256 CU = 1.5 blocks/CU with drain tails.
// 64-row tiles double the grid to 782 blocks (~3 resident blocks/CU, LDS cap
// 9, VGPR cap 4) and phase-stagger independent small blocks (the v5-vs-v6
// k_mlp lesson). GEMM stays 16 rows/wave; weight re-reads double to 50MB —
// L2-absorbed coalesced streams.
__global__ __launch_bounds__(256, 4) void k_fused(const unsigned short* __restrict__ selfB,
                                                  const int* __restrict__ row_ptr,
                                                  const int* __restrict__ colA,
                                                  const unsigned short* __restrict__ BT,
                                                  const float* __restrict__ bias,
                                                  unsigned short* __restrict__ Hout,
                                                  int M, int relu) {
    __shared__ unsigned short mt[64][136];    // means; reused as output tile
    const int tid = threadIdx.x;
    const int wv = tid >> 6, lane = tid & 63;
    const int q = lane >> 4, ql = lane & 15;
    const int r0 = blockIdx.x * 64;

    // prefetch all 4 rounds' row bounds + first-chunk colA
    int sA[4], eA[4], ceA[4];
#pragma unroll
    for (int r = 0; r < 4; r++) {
        int i = r * 16 + wv * 4 + q;           // 0..63
        int wc = min(r0 + i, M - 1);
        sA[r] = row_ptr[wc];
        eA[r] = row_ptr[wc + 1];
    }
#pragma unroll
    for (int r = 0; r < 4; r++)
        ceA[r] = (sA[r] + ql < eA[r]) ? colA[sA[r] + ql] : 0;

    // ---- phase 1: aggregate means for nodes r0..r0+63 into mt ----
#pragma unroll 1
    for (int r = 0; r < 4; r++) {
        int i = r * 16 + wv * 4 + q;           // 0..63
        bool act = (r0 + i < M);
        int s = sA[r], e = eA[r];
        float a[8];
#pragma unroll
        for (int j = 0; j < 8; j++) a[j] = 0.f;
        int ce = ceA[r];
        for (int base = s; base < e; base += 16) {
            int cnt = min(16, e - base);
            int ei[16];
#pragma unroll
            for (int j = 0; j < 16; j++) {
                int sl = (j < cnt) ? j : (cnt - 1);
                ei[j] = __shfl(ce, (q << 4) + sl, 64);
            }
            uint4 v[16];
#pragma unroll
            for (int j = 0; j < 16; j++)
                v[j] = *(const uint4*)(selfB + (size_t)ei[j] * 128 + ql * 8);
            // prefetch next chunk's colA BEFORE consuming v (v's loads are
            // older -> accumulate waits vmcnt(1), ce stays in flight)
            if (base + 16 < e) ce = (base + 16 + ql < e) ? colA[base + 16 + ql] : 0;
#pragma unroll
            for (int j = 0; j < 16; j += 2) {
                const unsigned* p0 = (const unsigned*)&v[j];
                const unsigned* p1 = (const unsigned*)&v[j + 1];
                if (j + 1 < cnt) {
#pragma unroll
                    for (int t = 0; t < 4; t++) {
                        a[2 * t] += b2f(p0[t] & 0xffff) + b2f(p1[t] & 0xffff);
                        a[2 * t + 1] += b2f(p0[t] >> 16) + b2f(p1[t] >> 16);
                    }
                } else if (j < cnt) {
#pragma unroll
                    for (int t = 0; t < 4; t++) {
                        a[2 * t] += b2f(p0[t] & 0xffff);
                        a[2 * t + 1] += b2f(p0[t] >> 16);
                    }
                }
            }
        }
        float rd = 1.0f / (float)max(e - s, 1);
        uint4 o;
        unsigned* op = (unsigned*)&o;
#pragma unroll
        for (int t = 0; t < 4; t++)
            op[t] = (unsigned)f2b(a[2 * t] * rd) | ((unsigned)f2b(a[2 * t + 1] * rd) << 16);
        if (act) *(uint4*)(&mt[i][ql * 8]) = o;
    }
    __syncthreads();

    // ---- phase 2: GEMM, 16 rows/wave (4 waves x 16 = 64 rows);
    // K 0..127 = self (global), 128..255 = mean (LDS)
    const int lr = lane & 15, lq = lane >> 4;
    const int arow = min(r0 + wv * 16 + lr, M - 1);
    f32x4 acc[8];
    f32x4 zero = {0.f, 0.f, 0.f, 0.f};
#pragma unroll
    for (int ct = 0; ct < 8; ct++) acc[ct] = zero;
#pragma unroll
    for (int kbi = 0; kbi < 8; kbi++) {
        bf16x8 wf[8];
#pragma unroll
        for (int ct = 0; ct < 8; ct++)
            wf[ct] = *(const bf16x8*)(BT + ((size_t)(kbi * 8 + ct) * 64 + lane) * 8);
        bf16x8 af;
        if (kbi < 4) {
            af = *(const bf16x8*)(selfB + (size_t)arow * 128 + kbi * 32 + lq * 8);
        } else {
            af = *(const bf16x8*)(&mt[arow - r0][(kbi - 4) * 32 + lq * 8]);
        }
#pragma unroll
        for (int ct = 0; ct < 8; ct++)
            acc[ct] = __builtin_amdgcn_mfma_f32_16x16x32_bf16(af, wf[ct], acc[ct], 0, 0, 0);
    }
    // all waves must finish READING mt before it is reused as the output tile
    __syncthreads();
#pragma unroll
    for (int ct = 0; ct < 8; ct++) {
        int colc = ct * 16 + lr;
        float bv = bias[colc];
#pragma unroll
        for (int r = 0; r < 4; r++) {
            float v = acc[ct][r] + bv;
            if (relu) v = fmaxf(v, 0.f);
            mt[wv * 16 + lq * 4 + r][colc] = f2b(v);
        }
    }
    __syncthreads();
    // vectorized store: 4 lanes/row, 4x16B/lane -> full-line 64B segments
    int rr = tid >> 2, cc = tid & 3;           // 64 rows x 4 lanes
    int grow = r0 + rr;
    if (grow < M) {
#pragma unroll
        for (int c = 0; c < 4; c++) {
            int so = c * 32 + cc * 8;
            *(uint4*)(Hout + (size_t)grow * 128 + so) = *(const uint4*)(&mt[rr][so]);
        }
    }
}

// ---- decoder MLP v11 (kept): persistent 8-wave blocks, weights in LDS,
// static schedule, single-buffer gather prefetch. At its gather-service
// floor (~37-40us, rounds 4-7) — no further edits.
__global__ __launch_bounds__(512, 2) void k_mlp(const unsigned short* __restrict__ h2b,
                                                const int* __restrict__ pos_src,
                                                const int* __restrict__ pos_dst,
                                                const int* __restrict__ neg_src,
                                                const int* __restrict__ neg_dst,
                                                const unsigned short* __restrict__ WdT1,
                                                const unsigned short* __restrict__ WdT2,
                                                const float* __restrict__ bd1,
                                                const float* __restrict__ bd2,
                                                const float* __restrict__ Wd3,
                                                const float* __restrict__ bd3,
                                                float* __restrict__ out, int P2) {
    __shared__ unsigned short wds[32768];        // WdT1 | WdT2, fragment-linear
    __shared__ unsigned short t1[8][32][136];    // per-wave transpose slice
    const int tid = threadIdx.x;
    {   // stage 64KB of weights, coalesced: 4096 uint4 over 512 threads
        const uint4* s1 = (const uint4*)WdT1;
        const uint4* s2 = (const uint4*)WdT2;
        uint4* d = (uint4*)wds;
#pragma unroll
        for (int i = 0; i < 4; i++) d[tid + i * 512] = s1[tid + i * 512];
#pragma unroll
        for (int i = 0; i < 4; i++) d[2048 + tid + i * 512] = s2[tid + i * 512];
    }
    __syncthreads();
    const unsigned short* wd1 = wds;
    const unsigned short* wd2 = wds + 16384;
    const int wv = tid >> 6;
    const int lane = tid & 63, lr = lane & 15, lq = lane >> 4;
    const int nw = gridDim.x << 3;               // 2048 waves
    const int nt = P2 >> 5;                      // 6250 tiles (exact)

    uint4 z[16];
    auto ISSUE = [&](int tile) {
        const int row0 = tile * 32;
        int p0 = min(row0 + lr, P2 - 1);
        int p1 = min(row0 + 16 + lr, P2 - 1);
        int s0i = (p0 < N_PAIRS) ? pos_src[p0] : neg_src[p0 - N_PAIRS];
        int d0i = (p0 < N_PAIRS) ? pos_dst[p0] : neg_dst[p0 - N_PAIRS];
        int s1i = (p1 < N_PAIRS) ? pos_src[p1] : neg_src[p1 - N_PAIRS];
        int d1i = (p1 < N_PAIRS) ? pos_dst[p1] : neg_dst[p1 - N_PAIRS];
#pragma unroll
        for (int kb = 0; kb < 4; kb++) {
            int ka = kb * 32 + lq * 8;
            z[kb]      = *(const uint4*)(h2b + (size_t)s0i * 128 + ka);
            z[4 + kb]  = *(const uint4*)(h2b + (size_t)d0i * 128 + ka);
            z[8 + kb]  = *(const uint4*)(h2b + (size_t)s1i * 128 + ka);
            z[12 + kb] = *(const uint4*)(h2b + (size_t)d1i * 128 + ka);
        }
    };

    bf16x8 af0[4], af1[4];
    auto REPACK = [&]() {
#pragma unroll
        for (int kb = 0; kb < 4; kb++) {
            unsigned r0v[4], r1v[4];
            const unsigned* a0p = (const unsigned*)&z[kb];
            const unsigned* b0p = (const unsigned*)&z[4 + kb];
            const unsigned* a1p = (const unsigned*)&z[8 + kb];
            const unsigned* b1p = (const unsigned*)&z[12 + kb];
#pragma unroll
            for (int j = 0; j < 4; j++) {
                unsigned short lo0 = f2b(b2f(a0p[j] & 0xffff) * b2f(b0p[j] & 0xffff));
                unsigned short hi0 = f2b(b2f(a0p[j] >> 16) * b2f(b0p[j] >> 16));
                r0v[j] = (unsigned)lo0 | ((unsigned)hi0 << 16);
                unsigned short lo1 = f2b(b2f(a1p[j] & 0xffff) * b2f(b1p[j] & 0xffff));
                unsigned short hi1 = f2b(b2f(a1p[j] >> 16) * b2f(b1p[j] >> 16));
                r1v[j] = (unsigned)lo1 | ((unsigned)hi1 << 16);
            }
            af0[kb] = *(const bf16x8*)r0v;
            af1[kb] = *(const bf16x8*)r1v;
        }
    };

    auto COMPUTE_REST = [&](int tile) {
        const int row0 = tile * 32;
        f32x4 zero = {0.f, 0.f, 0.f, 0.f};
        f32x4 acc[2][8];
#pragma unroll
        for (int m = 0; m < 2; m++)
#pragma unroll
            for (int ct = 0; ct < 8; ct++) acc[m][ct] = zero;
#pragma unroll
        for (int kb = 0; kb < 4; kb++) {
            bf16x8 wf[8];
#pragma unroll
            for (int ct = 0; ct < 8; ct++)
                wf[ct] = *(const bf16x8*)(wd1 + ((kb * 8 + ct) * 64 + lane) * 8);
#pragma unroll
            for (int ct = 0; ct < 8; ct++) {
                acc[0][ct] = __builtin_amdgcn_mfma_f32_16x16x32_bf16(af0[kb], wf[ct], acc[0][ct], 0, 0, 0);
                acc[1][ct] = __builtin_amdgcn_mfma_f32_16x16x32_bf16(af1[kb], wf[ct], acc[1][ct], 0, 0, 0);
            }
        }
#pragma unroll
        for (int m = 0; m < 2; m++)
#pragma unroll
            for (int ct = 0; ct < 8; ct++) {
                int colc = ct * 16 + lr;
                float bv = bd1[colc];
#pragma unroll
                for (int r = 0; r < 4; r++) {
                    float v = fmaxf(acc[m][ct][r] + bv, 0.f);
                    t1[wv][m * 16 + lq * 4 + r][colc] = f2b(v);
                }
            }
        // per-wave sync: slice t1[wv] is wave-private; drain this wave's DS ops.
        asm volatile("s_waitcnt lgkmcnt(0)" ::: "memory");
#pragma unroll
        for (int m = 0; m < 2; m++)
#pragma unroll
            for (int ct = 0; ct < 8; ct++) acc[m][ct] = zero;
#pragma unroll
        for (int kb = 0; kb < 4; kb++) {
            int ka = kb * 32 + lq * 8;
            bf16x8 wf[8];
#pragma unroll
            for (int ct = 0; ct < 8; ct++)
                wf[ct] = *(const bf16x8*)(wd2 + ((kb * 8 + ct) * 64 + lane) * 8);
            bf16x8 bf0 = *(const bf16x8*)(&t1[wv][lr][ka]);
            bf16x8 bf1 = *(const bf16x8*)(&t1[wv][16 + lr][ka]);
#pragma unroll
            for (int ct = 0; ct < 8; ct++) {
                acc[0][ct] = __builtin_amdgcn_mfma_f32_16x16x32_bf16(bf0, wf[ct], acc[0][ct], 0, 0, 0);
                acc[1][ct] = __builtin_amdgcn_mfma_f32_16x16x32_bf16(bf1, wf[ct], acc[1][ct], 0, 0, 0);
            }
        }
        float sc[2][4] = {{0.f, 0.f, 0.f, 0.f}, {0.f, 0.f, 0.f, 0.f}};
#pragma unroll
        for (int ct = 0; ct < 8; ct++) {
            int colc = ct * 16 + lr;
            float bv = bd2[colc];
            float w3 = Wd3[colc];
#pragma unroll
            for (int m = 0; m < 2; m++)
#pragma unroll
                for (int r = 0; r < 4; r++) {
                    float v = fmaxf(acc[m][ct][r] + bv, 0.f);
                    sc[m][r] += v * w3;
                }
        }
#pragma unroll
        for (int mm = 1; mm < 16; mm <<= 1)
#pragma unroll
            for (int m = 0; m < 2; m++)
#pragma unroll
                for (int r = 0; r < 4; r++) sc[m][r] += __shfl_xor(sc[m][r], mm, 64);
        if (lr == 0) {
            float b3 = bd3[0];
#pragma unroll
            for (int m = 0; m < 2; m++)
#pragma unroll
                for (int r = 0; r < 4; r++) {
                    int g = row0 + m * 16 + lq * 4 + r;
                    if (g < P2) out[g] = sc[m][r] + b3;
                }
        }
    };

    int t = blockIdx.x * 8 + wv;
    if (t >= nt) return;
    ISSUE(t);
    while (true) {
        REPACK();                       // waits on z, then z is dead
        int tn = t + nw;
        if (tn < nt) ISSUE(tn);         // next tile's loads fly under compute
        COMPUTE_REST(t);
        if (tn >= nt) break;
        t = tn;
    }
}

static inline size_t alignup(size_t v) { return (v + 255) & ~(size_t)255; }

extern "C" void kernel_launch(void* const* d_in, const int* in_sizes, int n_in,
                              void* d_out, int out_size, void* d_ws, size_t ws_size,
                              hipStream_t stream) {
    const float* x = (const float*)d_in[0];
    const int* edge_src = (const int*)d_in[1];
    const int* edge_dst = (const int*)d_in[2];
    const int* pos_src = (const int*)d_in[3];
    const int* pos_dst = (const int*)d_in[4];
    const int* neg_src = (const int*)d_in[5];
    const int* neg_dst = (const int*)d_in[6];
    const float* Ws1 = (const float*)d_in[7];
    const float* Wn1 = (const float*)d_in[8];
    const float* b1 = (const float*)d_in[9];
    const float* Ws2 = (const float*)d_in[10];
    const float* Wn2 = (const float*)d_in[11];
    const float* b2 = (const float*)d_in[12];
    const float* Wd1 = (const float*)d_in[13];
    const float* bd1 = (const float*)d_in[14];
    const float* Wd2 = (const float*)d_in[15];
    const float* bd2 = (const float*)d_in[16];
    const float* Wd3 = (const float*)d_in[17];
    const float* bd3 = (const float*)d_in[18];
    float* out = (float*)d_out;

    char* p = (char*)d_ws;
    int* deg = (int*)p;            p += alignup(N_NODES * 4);
    int* row_ptr = (int*)p;        p += alignup((N_NODES + 1) * 4);
    int* cursor = (int*)p;         p += alignup(N_NODES * 4);
    int* bsum = (int*)p;           p += alignup(64 * 4);
    int* colA = (int*)p;           p += alignup(N_EDGES * 4);
    unsigned short* h1 = (unsigned short*)p;  p += alignup((size_t)N_NODES * 128 * 2);
    unsigned short* h2b = (unsigned short*)p; p += alignup((size_t)N_NODES * 128 * 2);
    unsigned short* WT1 = (unsigned short*)p;  p += alignup(32768 * 2);
    unsigned short* WT2 = (unsigned short*)p;  p += alignup(32768 * 2);
    unsigned short* WdT1 = (unsigned short*)p; p += alignup(16384 * 2);
    unsigned short* WdT2 = (unsigned short*)p; p += alignup(16384 * 2);
    // compact bf16 copy of x, aliased onto h2b (fully consumed by fused layer 1
    // before fused layer 2 writes h2b)
    unsigned short* xb16 = h2b;

    hipMemsetAsync(deg, 0, N_NODES * 4, stream);

    // merged convert + weight-prep + degree histogram
    k_prep<<<(N_NODES * 32 + 255) / 256, 256, 0, stream>>>(
        x, xb16, edge_dst, deg,
        Ws1, Wn1, Ws2, Wn2, Wd1, Wd2, WT1, WT2, WdT1, WdT2);

    int nb1 = (N_NODES + 1023) / 1024;
    k_scan1<<<nb1, 1024, 0, stream>>>(deg, row_ptr, bsum, N_NODES);
    k_add<<<nb1, 1024, 0, stream>>>(row_ptr, cursor, bsum, N_NODES);
    k_scatter<<<(N_EDGES + 255) / 256, 256, 0, stream>>>(edge_src, edge_dst, cursor, colA);

    int nblk = (N_NODES + 63) / 64;   // 782 blocks: ~3 resident blocks/CU

    // fused layer 1: agg(xb16) + GEMM -> h1 (relu)
    k_fused<<<nblk, 256, 0, stream>>>(xb16, row_ptr, colA, WT1, b1, h1, N_NODES, 1);
    // fused layer 2: agg(h1) + GEMM -> h2b (no act)
    k_fused<<<nblk, 256, 0, stream>>>(h1, row_ptr, colA, WT2, b2, h2b, N_NODES, 0);

    // decoder: persistent 8-wave blocks, LDS weights, static schedule,
    // single-buffer gather prefetch
    k_mlp<<<256, 512, 0, stream>>>(h2b, pos_src, pos_dst, neg_src, neg_dst,
                                   WdT1, WdT2, bd1, bd2, Wd3, bd3,
                                   out, N_PAIRS * 2);
}

// Round 14
// 265.133 us; speedup vs baseline: 1.1326x; 1.0184x over previous
//
#include <hip/hip_runtime.h>
#include <hip/hip_bf16.h>

#define N_NODES 50000
#define N_EDGES 600000
#define N_PAIRS 100000

typedef __attribute__((ext_vector_type(8))) short bf16x8;
typedef __attribute__((ext_vector_type(4))) float f32x4;

__device__ inline unsigned short f2b(float f) {
    unsigned u = __float_as_uint(f);
    unsigned r = u + 0x7fff + ((u >> 16) & 1);
    return (unsigned short)(r >> 16);
}
__device__ inline float b2f(unsigned short h) {
    return __uint_as_float(((unsigned)h) << 16);
}

// ---- MERGED prep: x->bf16 compact convert + edge-degree histogram +
// FRAGMENT-LINEAR weight transposes.
__global__ void k_prep(const float* __restrict__ x, unsigned short* __restrict__ xb16,
                       const int* __restrict__ edge_dst, int* __restrict__ deg,
                       const float* __restrict__ Ws1, const float* __restrict__ Wn1,
                       const float* __restrict__ Ws2, const float* __restrict__ Wn2,
                       const float* __restrict__ Wd1, const float* __restrict__ Wd2,
                       unsigned short* __restrict__ WT1, unsigned short* __restrict__ WT2,
                       unsigned short* __restrict__ WdT1, unsigned short* __restrict__ WdT2) {
    int idx = blockIdx.x * blockDim.x + threadIdx.x;
    if (idx < N_EDGES) atomicAdd(&deg[edge_dst[idx]], 1);
    if (idx < 98304) {
        int id = idx;
        if (id < 32768) {                      // WT1: K=256 (Ws1 | Wn1)
            int j = id & 7, g = id >> 3;
            int lane = g & 63, t = g >> 6;
            int ct = t & 7, kb = t >> 3;
            int k = kb * 32 + (lane >> 4) * 8 + j, n = ct * 16 + (lane & 15);
            float v = (k < 128) ? Ws1[k * 128 + n] : Wn1[(k - 128) * 128 + n];
            WT1[id] = f2b(v);
        } else if (id < 65536) {               // WT2: K=256 (Ws2 | Wn2)
            int r = id - 32768;
            int j = r & 7, g = r >> 3;
            int lane = g & 63, t = g >> 6;
            int ct = t & 7, kb = t >> 3;
            int k = kb * 32 + (lane >> 4) * 8 + j, n = ct * 16 + (lane & 15);
            float v = (k < 128) ? Ws2[k * 128 + n] : Wn2[(k - 128) * 128 + n];
            WT2[r] = f2b(v);
        } else if (id < 81920) {               // WdT1: K=128
            int r = id - 65536;
            int j = r & 7, g = r >> 3;
            int lane = g & 63, t = g >> 6;
            int ct = t & 7, kb = t >> 3;
            int k = kb * 32 + (lane >> 4) * 8 + j, n = ct * 16 + (lane & 15);
            WdT1[r] = f2b(Wd1[k * 128 + n]);
        } else {                               // WdT2: K=128
            int r = id - 81920;
            int j = r & 7, g = r >> 3;
            int lane = g & 63, t = g >> 6;
            int ct = t & 7, kb = t >> 3;
            int k = kb * 32 + (lane >> 4) * 8 + j, n = ct * 16 + (lane & 15);
            WdT2[r] = f2b(Wd2[k * 128 + n]);
        }
    }
    if (idx >= N_NODES * 32) return;
    int row = idx >> 5, c4 = (idx & 31) * 4;
    float4 v = *(const float4*)(x + row * 128 + c4);
    unsigned lo = (unsigned)f2b(v.x) | ((unsigned)f2b(v.y) << 16);
    unsigned hi = (unsigned)f2b(v.z) | ((unsigned)f2b(v.w) << 16);
    uint2 o; o.x = lo; o.y = hi;
    *(uint2*)(xb16 + row * 128 + c4) = o;
}

// ---- CSR build ----
__global__ void k_scan1(const int* __restrict__ deg, int* __restrict__ row_ptr,
                        int* __restrict__ bsum, int n) {
    __shared__ int tmp[1024];
    int i = blockIdx.x * 1024 + threadIdx.x;
    int d = (i < n) ? deg[i] : 0;
    tmp[threadIdx.x] = d;
    __syncthreads();
    int run = d;
    for (int off = 1; off < 1024; off <<= 1) {
        int t = (threadIdx.x >= off) ? tmp[threadIdx.x - off] : 0;
        __syncthreads();
        run += t;
        tmp[threadIdx.x] = run;
        __syncthreads();
    }
    if (i < n) row_ptr[i] = run - d;       // block-local exclusive
    if (threadIdx.x == 1023) bsum[blockIdx.x] = run;   // block total
}

// fused: global prefix from bsum totals computed per block (<=49 adds)
__global__ void k_add(int* __restrict__ row_ptr, int* __restrict__ cursor,
                      const int* __restrict__ bsum, int n) {
    __shared__ int prefix;
    if (threadIdx.x == 0) {
        int acc = 0;
        for (int j = 0; j < (int)blockIdx.x; j++) acc += bsum[j];
        prefix = acc;
    }
    __syncthreads();
    int i = blockIdx.x * 1024 + threadIdx.x;
    if (i < n) {
        int v = row_ptr[i] + prefix;
        row_ptr[i] = v;
        cursor[i] = v;
    }
    if (i == 0) row_ptr[n] = N_EDGES;
}

__global__ void k_scatter(const int* __restrict__ src, const int* __restrict__ dst,
                          int* __restrict__ cursor, int* __restrict__ colA) {
    int e = blockIdx.x * blockDim.x + threadIdx.x;
    if (e < N_EDGES) {
        int d = dst[e];
        int slot = atomicAdd(&cursor[d], 1);
        colA[slot] = src[e];
    }
}

// ---- FUSED SAGE layer v5: 32-ROW TILES / 2-WAVE BLOCKS (1563 blocks,
// ~6 resident blocks/CU). Continues the measured grid-granularity lever:
// 128->64 rows (391->782 blocks) was -6us; the gather phase is latency-bound
// and wants maximum resident independent blocks. Caps: VGPR 104 <= 128
// (launch_bounds(128,4)) -> 8 blocks/CU; LDS 8.7KB -> 18. Weight re-reads
// ~100MB/layer — coalesced L2 streams (~+3us, round-3 lesson: cheap).
__global__ __launch_bounds__(128, 4) void k_fused(const unsigned short* __restrict__ selfB,
                                                  const int* __restrict__ row_ptr,
                                                  const int* __restrict__ colA,
                                                  const unsigned short* __restrict__ BT,
                                                  const float* __restrict__ bias,
                                                  unsigned short* __restrict__ Hout,
                                                  int M, int relu) {
    __shared__ unsigned short mt[32][136];    // means; reused as output tile
    const int tid = threadIdx.x;
    const int wv = tid >> 6, lane = tid & 63;    // wv in {0,1}
    const int q = lane >> 4, ql = lane & 15;
    const int r0 = blockIdx.x * 32;

    // prefetch all 4 rounds' row bounds + first-chunk colA
    int sA[4], eA[4], ceA[4];
#pragma unroll
    for (int r = 0; r < 4; r++) {
        int i = r * 8 + wv * 4 + q;              // 0..31
        int wc = min(r0 + i, M - 1);
        sA[r] = row_ptr[wc];
        eA[r] = row_ptr[wc + 1];
    }
#pragma unroll
    for (int r = 0; r < 4; r++)
        ceA[r] = (sA[r] + ql < eA[r]) ? colA[sA[r] + ql] : 0;

    // ---- phase 1: aggregate means for nodes r0..r0+31 into mt ----
#pragma unroll 1
    for (int r = 0; r < 4; r++) {
        int i = r * 8 + wv * 4 + q;              // 0..31
        bool act = (r0 + i < M);
        int s = sA[r], e = eA[r];
        float a[8];
#pragma unroll
        for (int j = 0; j < 8; j++) a[j] = 0.f;
        int ce = ceA[r];
        for (int base = s; base < e; base += 16) {
            int cnt = min(16, e - base);
            int ei[16];
#pragma unroll
            for (int j = 0; j < 16; j++) {
                int sl = (j < cnt) ? j : (cnt - 1);
                ei[j] = __shfl(ce, (q << 4) + sl, 64);
            }
            uint4 v[16];
#pragma unroll
            for (int j = 0; j < 16; j++)
                v[j] = *(const uint4*)(selfB + (size_t)ei[j] * 128 + ql * 8);
            // prefetch next chunk's colA BEFORE consuming v (v's loads are
            // older -> accumulate waits vmcnt(1), ce stays in flight)
            if (base + 16 < e) ce = (base + 16 + ql < e) ? colA[base + 16 + ql] : 0;
#pragma unroll
            for (int j = 0; j < 16; j += 2) {
                const unsigned* p0 = (const unsigned*)&v[j];
                const unsigned* p1 = (const unsigned*)&v[j + 1];
                if (j + 1 < cnt) {
#pragma unroll
                    for (int t = 0; t < 4; t++) {
                        a[2 * t] += b2f(p0[t] & 0xffff) + b2f(p1[t] & 0xffff);
                        a[2 * t + 1] += b2f(p0[t] >> 16) + b2f(p1[t] >> 16);
                    }
                } else if (j < cnt) {
#pragma unroll
                    for (int t = 0; t < 4; t++) {
                        a[2 * t] += b2f(p0[t] & 0xffff);
                        a[2 * t + 1] += b2f(p0[t] >> 16);
                    }
                }
            }
        }
        float rd = 1.0f / (float)max(e - s, 1);
        uint4 o;
        unsigned* op = (unsigned*)&o;
#pragma unroll
        for (int t = 0; t < 4; t++)
            op[t] = (unsigned)f2b(a[2 * t] * rd) | ((unsigned)f2b(a[2 * t + 1] * rd) << 16);
        if (act) *(uint4*)(&mt[i][ql * 8]) = o;
    }
    __syncthreads();

    // ---- phase 2: GEMM, 16 rows/wave (2 waves x 16 = 32 rows);
    // K 0..127 = self (global), 128..255 = mean (LDS)
    const int lr = lane & 15, lq = lane >> 4;
    const int arow = min(r0 + wv * 16 + lr, M - 1);
    f32x4 acc[8];
    f32x4 zero = {0.f, 0.f, 0.f, 0.f};
#pragma unroll
    for (int ct = 0; ct < 8; ct++) acc[ct] = zero;
#pragma unroll
    for (int kbi = 0; kbi < 8; kbi++) {
        bf16x8 wf[8];
#pragma unroll
        for (int ct = 0; ct < 8; ct++)
            wf[ct] = *(const bf16x8*)(BT + ((size_t)(kbi * 8 + ct) * 64 + lane) * 8);
        bf16x8 af;
        if (kbi < 4) {
            af = *(const bf16x8*)(selfB + (size_t)arow * 128 + kbi * 32 + lq * 8);
        } else {
            af = *(const bf16x8*)(&mt[arow - r0][(kbi - 4) * 32 + lq * 8]);
        }
#pragma unroll
        for (int ct = 0; ct < 8; ct++)
            acc[ct] = __builtin_amdgcn_mfma_f32_16x16x32_bf16(af, wf[ct], acc[ct], 0, 0, 0);
    }
    // all waves must finish READING mt before it is reused as the output tile
    __syncthreads();
#pragma unroll
    for (int ct = 0; ct < 8; ct++) {
        int colc = ct * 16 + lr;
        float bv = bias[colc];
#pragma unroll
        for (int r = 0; r < 4; r++) {
            float v = acc[ct][r] + bv;
            if (relu) v = fmaxf(v, 0.f);
            mt[wv * 16 + lq * 4 + r][colc] = f2b(v);
        }
    }
    __syncthreads();
    // vectorized store: 4 lanes/row, 4x16B/lane -> full-line 64B segments
    int rr = tid >> 2, cc = tid & 3;           // 32 rows x 4 lanes
    int grow = r0 + rr;
    if (grow < M) {
#pragma unroll
        for (int c = 0; c < 4; c++) {
            int so = c * 32 + cc * 8;
            *(uint4*)(Hout + (size_t)grow * 128 + so) = *(const uint4*)(&mt[rr][so]);
        }
    }
}

// ---- decoder MLP v11 (kept): persistent 8-wave blocks, weights in LDS,
// static schedule, single-buffer gather prefetch. At its gather-service
// floor (~37-40us, rounds 4-7) — no further edits.
__global__ __launch_bounds__(512, 2) void k_mlp(const unsigned short* __restrict__ h2b,
                                                const int* __restrict__ pos_src,
                                                const int* __restrict__ pos_dst,
                                                const int* __restrict__ neg_src,
                                                const int* __restrict__ neg_dst,
                                                const unsigned short* __restrict__ WdT1,
                                                const unsigned short* __restrict__ WdT2,
                                                const float* __restrict__ bd1,
                                                const float* __restrict__ bd2,
                                                const float* __restrict__ Wd3,
                                                const float* __restrict__ bd3,
                                                float* __restrict__ out, int P2) {
    __shared__ unsigned short wds[32768];        // WdT1 | WdT2, fragment-linear
    __shared__ unsigned short t1[8][32][136];    // per-wave transpose slice
    const int tid = threadIdx.x;
    {   // stage 64KB of weights, coalesced: 4096 uint4 over 512 threads
        const uint4* s1 = (const uint4*)WdT1;
        const uint4* s2 = (const uint4*)WdT2;
        uint4* d = (uint4*)wds;
#pragma unroll
        for (int i = 0; i < 4; i++) d[tid + i * 512] = s1[tid + i * 512];
#pragma unroll
        for (int i = 0; i < 4; i++) d[2048 + tid + i * 512] = s2[tid + i * 512];
    }
    __syncthreads();
    const unsigned short* wd1 = wds;
    const unsigned short* wd2 = wds + 16384;
    const int wv = tid >> 6;
    const int lane = tid & 63, lr = lane & 15, lq = lane >> 4;
    const int nw = gridDim.x << 3;               // 2048 waves
    const int nt = P2 >> 5;                      // 6250 tiles (exact)

    uint4 z[16];
    auto ISSUE = [&](int tile) {
        const int row0 = tile * 32;
        int p0 = min(row0 + lr, P2 - 1);
        int p1 = min(row0 + 16 + lr, P2 - 1);
        int s0i = (p0 < N_PAIRS) ? pos_src[p0] : neg_src[p0 - N_PAIRS];
        int d0i = (p0 < N_PAIRS) ? pos_dst[p0] : neg_dst[p0 - N_PAIRS];
        int s1i = (p1 < N_PAIRS) ? pos_src[p1] : neg_src[p1 - N_PAIRS];
        int d1i = (p1 < N_PAIRS) ? pos_dst[p1] : neg_dst[p1 - N_PAIRS];
#pragma unroll
        for (int kb = 0; kb < 4; kb++) {
            int ka = kb * 32 + lq * 8;
            z[kb]      = *(const uint4*)(h2b + (size_t)s0i * 128 + ka);
            z[4 + kb]  = *(const uint4*)(h2b + (size_t)d0i * 128 + ka);
            z[8 + kb]  = *(const uint4*)(h2b + (size_t)s1i * 128 + ka);
            z[12 + kb] = *(const uint4*)(h2b + (size_t)d1i * 128 + ka);
        }
    };

    bf16x8 af0[4], af1[4];
    auto REPACK = [&]() {
#pragma unroll
        for (int kb = 0; kb < 4; kb++) {
            unsigned r0v[4], r1v[4];
            const unsigned* a0p = (const unsigned*)&z[kb];
            const unsigned* b0p = (const unsigned*)&z[4 + kb];
            const unsigned* a1p = (const unsigned*)&z[8 + kb];
            const unsigned* b1p = (const unsigned*)&z[12 + kb];
#pragma unroll
            for (int j = 0; j < 4; j++) {
                unsigned short lo0 = f2b(b2f(a0p[j] & 0xffff) * b2f(b0p[j] & 0xffff));
                unsigned short hi0 = f2b(b2f(a0p[j] >> 16) * b2f(b0p[j] >> 16));
                r0v[j] = (unsigned)lo0 | ((unsigned)hi0 << 16);
                unsigned short lo1 = f2b(b2f(a1p[j] & 0xffff) * b2f(b1p[j] & 0xffff));
                unsigned short hi1 = f2b(b2f(a1p[j] >> 16) * b2f(b1p[j] >> 16));
                r1v[j] = (unsigned)lo1 | ((unsigned)hi1 << 16);
            }
            af0[kb] = *(const bf16x8*)r0v;
            af1[kb] = *(const bf16x8*)r1v;
        }
    };

    auto COMPUTE_REST = [&](int tile) {
        const int row0 = tile * 32;
        f32x4 zero = {0.f, 0.f, 0.f, 0.f};
        f32x4 acc[2][8];
#pragma unroll
        for (int m = 0; m < 2; m++)
#pragma unroll
            for (int ct = 0; ct < 8; ct++) acc[m][ct] = zero;
#pragma unroll
        for (int kb = 0; kb < 4; kb++) {
            bf16x8 wf[8];
#pragma unroll
            for (int ct = 0; ct < 8; ct++)
                wf[ct] = *(const bf16x8*)(wd1 + ((kb * 8 + ct) * 64 + lane) * 8);
#pragma unroll
            for (int ct = 0; ct < 8; ct++) {
                acc[0][ct] = __builtin_amdgcn_mfma_f32_16x16x32_bf16(af0[kb], wf[ct], acc[0][ct], 0, 0, 0);
                acc[1][ct] = __builtin_amdgcn_mfma_f32_16x16x32_bf16(af1[kb], wf[ct], acc[1][ct], 0, 0, 0);
            }
        }
#pragma unroll
        for (int m = 0; m < 2; m++)
#pragma unroll
            for (int ct = 0; ct < 8; ct++) {
                int colc = ct * 16 + lr;
                float bv = bd1[colc];
#pragma unroll
                for (int r = 0; r < 4; r++) {
                    float v = fmaxf(acc[m][ct][r] + bv, 0.f);
                    t1[wv][m * 16 + lq * 4 + r][colc] = f2b(v);
                }
            }
        // per-wave sync: slice t1[wv] is wave-private; drain this wave's DS ops.
        asm volatile("s_waitcnt lgkmcnt(0)" ::: "memory");
#pragma unroll
        for (int m = 0; m < 2; m++)
#pragma unroll
            for (int ct = 0; ct < 8; ct++) acc[m][ct] = zero;
#pragma unroll
        for (int kb = 0; kb < 4; kb++) {
            int ka = kb * 32 + lq * 8;
            bf16x8 wf[8];
#pragma unroll
            for (int ct = 0; ct < 8; ct++)
                wf[ct] = *(const bf16x8*)(wd2 + ((kb * 8 + ct) * 64 + lane) * 8);
            bf16x8 bf0 = *(const bf16x8*)(&t1[wv][lr][ka]);
            bf16x8 bf1 = *(const bf16x8*)(&t1[wv][16 + lr][ka]);
#pragma unroll
            for (int ct = 0; ct < 8; ct++) {
                acc[0][ct] = __builtin_amdgcn_mfma_f32_16x16x32_bf16(bf0, wf[ct], acc[0][ct], 0, 0, 0);
                acc[1][ct] = __builtin_amdgcn_mfma_f32_16x16x32_bf16(bf1, wf[ct], acc[1][ct], 0, 0, 0);
            }
        }
        float sc[2][4] = {{0.f, 0.f, 0.f, 0.f}, {0.f, 0.f, 0.f, 0.f}};
#pragma unroll
        for (int ct = 0; ct < 8; ct++) {
            int colc = ct * 16 + lr;
            float bv = bd2[colc];
            float w3 = Wd3[colc];
#pragma unroll
            for (int m = 0; m < 2; m++)
#pragma unroll
                for (int r = 0; r < 4; r++) {
                    float v = fmaxf(acc[m][ct][r] + bv, 0.f);
                    sc[m][r] += v * w3;
                }
        }
#pragma unroll
        for (int mm = 1; mm < 16; mm <<= 1)
#pragma unroll
            for (int m = 0; m < 2; m++)
#pragma unroll
                for (int r = 0; r < 4; r++) sc[m][r] += __shfl_xor(sc[m][r], mm, 64);
        if (lr == 0) {
            float b3 = bd3[0];
#pragma unroll
            for (int m = 0; m < 2; m++)
#pragma unroll
                for (int r = 0; r < 4; r++) {
                    int g = row0 + m * 16 + lq * 4 + r;
                    if (g < P2) out[g] = sc[m][r] + b3;
                }
        }
    };

    int t = blockIdx.x * 8 + wv;
    if (t >= nt) return;
    ISSUE(t);
    while (true) {
        REPACK();                       // waits on z, then z is dead
        int tn = t + nw;
        if (tn < nt) ISSUE(tn);         // next tile's loads fly under compute
        COMPUTE_REST(t);
        if (tn >= nt) break;
        t = tn;
    }
}

static inline size_t alignup(size_t v) { return (v + 255) & ~(size_t)255; }

extern "C" void kernel_launch(void* const* d_in, const int* in_sizes, int n_in,
                              void* d_out, int out_size, void* d_ws, size_t ws_size,
                              hipStream_t stream) {
    const float* x = (const float*)d_in[0];
    const int* edge_src = (const int*)d_in[1];
    const int* edge_dst = (const int*)d_in[2];
    const int* pos_src = (const int*)d_in[3];
    const int* pos_dst = (const int*)d_in[4];
    const int* neg_src = (const int*)d_in[5];
    const int* neg_dst = (const int*)d_in[6];
    const float* Ws1 = (const float*)d_in[7];
    const float* Wn1 = (const float*)d_in[8];
    const float* b1 = (const float*)d_in[9];
    const float* Ws2 = (const float*)d_in[10];
    const float* Wn2 = (const float*)d_in[11];
    const float* b2 = (const float*)d_in[12];
    const float* Wd1 = (const float*)d_in[13];
    const float* bd1 = (const float*)d_in[14];
    const float* Wd2 = (const float*)d_in[15];
    const float* bd2 = (const float*)d_in[16];
    const float* Wd3 = (const float*)d_in[17];
    const float* bd3 = (const float*)d_in[18];
    float* out = (float*)d_out;

    char* p = (char*)d_ws;
    int* deg = (int*)p;            p += alignup(N_NODES * 4);
    int* row_ptr = (int*)p;        p += alignup((N_NODES + 1) * 4);
    int* cursor = (int*)p;         p += alignup(N_NODES * 4);
    int* bsum = (int*)p;           p += alignup(64 * 4);
    int* colA = (int*)p;           p += alignup(N_EDGES * 4);
    unsigned short* h1 = (unsigned short*)p;  p += alignup((size_t)N_NODES * 128 * 2);
    unsigned short* h2b = (unsigned short*)p; p += alignup((size_t)N_NODES * 128 * 2);
    unsigned short* WT1 = (unsigned short*)p;  p += alignup(32768 * 2);
    unsigned short* WT2 = (unsigned short*)p;  p += alignup(32768 * 2);
    unsigned short* WdT1 = (unsigned short*)p; p += alignup(16384 * 2);
    unsigned short* WdT2 = (unsigned short*)p; p += alignup(16384 * 2);
    // compact bf16 copy of x, aliased onto h2b (fully consumed by fused layer 1
    // before fused layer 2 writes h2b)
    unsigned short* xb16 = h2b;

    hipMemsetAsync(deg, 0, N_NODES * 4, stream);

    // merged convert + weight-prep + degree histogram
    k_prep<<<(N_NODES * 32 + 255) / 256, 256, 0, stream>>>(
        x, xb16, edge_dst, deg,
        Ws1, Wn1, Ws2, Wn2, Wd1, Wd2, WT1, WT2, WdT1, WdT2);

    int nb1 = (N_NODES + 1023) / 1024;
    k_scan1<<<nb1, 1024, 0, stream>>>(deg, row_ptr, bsum, N_NODES);
    k_add<<<nb1, 1024, 0, stream>>>(row_ptr, cursor, bsum, N_NODES);
    k_scatter<<<(N_EDGES + 255) / 256, 256, 0, stream>>>(edge_src, edge_dst, cursor, colA);

    int nblk = (N_NODES + 31) / 32;   // 1563 blocks: ~6 resident blocks/CU

    // fused layer 1: agg(xb16) + GEMM -> h1 (relu)
    k_fused<<<nblk, 128, 0, stream>>>(xb16, row_ptr, colA, WT1, b1, h1, N_NODES, 1);
    // fused layer 2: agg(h1) + GEMM -> h2b (no act)
    k_fused<<<nblk, 128, 0, stream>>>(h1, row_ptr, colA, WT2, b2, h2b, N_NODES, 0);

    // decoder: persistent 8-wave blocks, LDS weights, static schedule,
    // single-buffer gather prefetch
    k_mlp<<<256, 512, 0, stream>>>(h2b, pos_src, pos_dst, neg_src, neg_dst,
                                   WdT1, WdT2, bd1, bd2, Wd3, bd3,
                                   out, N_PAIRS * 2);
}